// Round 7
// baseline (4592.842 us; speedup 1.0000x reference)
//
#include <hip/hip_runtime.h>
#include <cstdint>

// ---------------------------------------------------------------------------
// Red-black SOR Laplace solver, persistent kernel, f64, ONE barrier/iter.
// Round 7: bulk data (x ping-pong buffers) moved OFF the sc1 uncached path
// onto normal cached loads/stores; cross-XCD coherence via explicit
// release(wbl2)/acquire(buffer_inv) fences inside the grid barrier.
// sc1 atomics retained for the barrier control words only.
// Own plane persists in LDS across iterations (P[1] never re-staged).
// Stop when !(dv >= 0.05 && it <= 500)  [jax.lax.while_loop semantics].
// ---------------------------------------------------------------------------

#define NBLK 132
#define NTHR 1024
#define NW   (NTHR / 64)

constexpr int NJK   = 66;
constexpr int PLANE = 66 * 66;          // 4356
constexpr int HPL   = PLANE / 2;        // 2178
constexpr int NI    = 132;
constexpr int NTOT  = NI * PLANE;       // 574992
constexpr int CAPL  = HPL;              // list cap per color per plane
constexpr int NOUT  = 2 * 64 * 64 * 64; // 524288
constexpr int CTRL_U64 = 512;           // 32 lines x 16 u64 (128 B spacing)
constexpr unsigned long long CNT1   = 1ull << 44;
constexpr unsigned long long MASK44 = CNT1 - 1ull;

__global__ void sor_init_ctrl(unsigned long long* ctrl) {
  for (int i = threadIdx.x; i < CTRL_U64; i += blockDim.x) ctrl[i] = 0ull;
}

// padded flat coords -> original image flat index, or -1 if pad voxel
__device__ __forceinline__ int pad_label_idx(int ii, int jj, int kk) {
  int b  = (ii >= 66) ? 1 : 0;
  int pz = ii - 66 * b;
  if (pz < 1 || pz > 64 || jj < 1 || jj > 64 || kk < 1 || kk > 64) return -1;
  return ((b * 64 + (pz - 1)) * 64 + (jj - 1)) * 64 + (kk - 1);
}

__global__ __launch_bounds__(NTHR, 1)
void sor_main(const float* __restrict__ img, double* __restrict__ x0,
              double* __restrict__ x1, unsigned long long* __restrict__ ctrl,
              float* __restrict__ out) {
  __shared__ double P[3][PLANE];          // planes z-1, z, z+1 (104544 B)
  __shared__ double H[2][HPL];            // black-parity halves of z-2, z+2
  __shared__ unsigned short lsB[3][CAPL]; // black lists, planes z-1,z,z+1
  __shared__ unsigned short lsR[CAPL];    // red list, own plane
  __shared__ unsigned wsum[NW], woff[NW];
  __shared__ unsigned tot;
  __shared__ double redw[NW];
  __shared__ unsigned long long sh_sum;

  const int tid = threadIdx.x, bid = blockIdx.x;
  const int lane = tid & 63, wid = tid >> 6;
  const int z = bid;

  // ---- init own plane: global x0 AND persistent LDS copy P[1] ----
  {
    double* dst = x0 + (size_t)z * PLANE;
    for (int o = tid; o < PLANE; o += NTHR) {
      int j = o / NJK, k = o - j * NJK;
      int li = pad_label_idx(z, j, k);
      float L = (li >= 0) ? img[li] : 0.0f;
      double v = (L == 3.0f) ? 1.0 : 0.0;
      dst[o] = v;
      P[1][o] = v;
    }
  }

  // ---- build gm lists: black for z-1,z,z+1; red for z (stable o-order) ----
  int cntB[3], cntR = 0;
  const int CH = (PLANE + NTHR - 1) / NTHR;
  for (int pass = 0; pass < 4; ++pass) {
    const int zz = (pass < 3) ? (z - 1 + pass) : z;
    const int wpar = (pass < 3) ? 0 : 1;
    unsigned short* list = (pass < 3) ? lsB[pass] : lsR;
    const bool ok = (zz >= 0 && zz < NI);
    int c0 = tid * CH;
    int c1 = (c0 + CH < PLANE) ? (c0 + CH) : PLANE;
    unsigned cnt = 0;
    if (ok) {
      for (int o = c0; o < c1; ++o) {
        int j = o / NJK, k = o - j * NJK;
        if (((zz + j + k) & 1) != wpar) continue;
        int li = pad_label_idx(zz, j, k);
        float L = (li >= 0) ? img[li] : 0.0f;
        if (L == 1.0f) cnt++;
      }
    }
    unsigned incl = cnt;
    #pragma unroll
    for (int m = 1; m < 64; m <<= 1) {
      unsigned t = __shfl_up(incl, m, 64);
      if (lane >= m) incl += t;
    }
    __syncthreads();
    if (lane == 63) wsum[wid] = incl;
    __syncthreads();
    if (tid == 0) {
      unsigned a = 0;
      for (int w = 0; w < NW; ++w) { unsigned c = wsum[w]; woff[w] = a; a += c; }
      tot = a;
    }
    __syncthreads();
    unsigned p = (incl - cnt) + woff[wid];
    if (ok) {
      for (int o = c0; o < c1; ++o) {
        int j = o / NJK, k = o - j * NJK;
        if (((zz + j + k) & 1) != wpar) continue;
        int li = pad_label_idx(zz, j, k);
        float L = (li >= 0) ? img[li] : 0.0f;
        if (L == 1.0f) list[p++] = (unsigned short)o;
      }
    }
    __syncthreads();
    if (pass < 3) cntB[pass] = (int)tot; else cntR = (int)tot;
  }

  // ---- barrier: release fence -> sc1 arrival+dv payload -> poll ->
  //      acquire fence (every wave). Parity line sets, fixed-point dv. ----
  unsigned tgt[2] = {0u, 0u};
  unsigned long long prevc[2] = {0ull, 0ull};
  unsigned nbar = 0;

  auto barrier_payload = [&](bool withdv) -> unsigned long long {
    const unsigned par = nbar & 1u;
    tgt[par] += (unsigned)NBLK;
    __syncthreads();   // every wave: s_waitcnt vmcnt(0) -> stores are in L2
    if (tid == 0) {
      __builtin_amdgcn_fence(__ATOMIC_RELEASE, "agent");  // wbl2: L2 -> IF$
      unsigned long long pay = CNT1;
      if (withdv) {
        double s = redw[0];
        #pragma unroll
        for (int w = 1; w < NW; ++w) s += redw[w];
        pay += (unsigned long long)(s * 1048576.0 + 0.5);
      }
      __hip_atomic_fetch_add(&ctrl[(par * 16u + (unsigned)(bid & 15)) * 16u],
                             pay, __ATOMIC_RELAXED, __HIP_MEMORY_SCOPE_AGENT);
    }
    if (tid < 16) {
      const unsigned long long t64 = (unsigned long long)tgt[par] << 44;
      for (;;) {
        unsigned long long v =
            __hip_atomic_load(&ctrl[(par * 16u + (unsigned)tid) * 16u],
                              __ATOMIC_RELAXED, __HIP_MEMORY_SCOPE_AGENT);
        v += __shfl_xor(v, 1, 64);  v += __shfl_xor(v, 2, 64);
        v += __shfl_xor(v, 4, 64);  v += __shfl_xor(v, 8, 64);
        if (v >= t64) { if (tid == 0) sh_sum = v; break; }
        __builtin_amdgcn_s_sleep(1);
      }
    }
    __syncthreads();
    __builtin_amdgcn_fence(__ATOMIC_ACQUIRE, "agent");  // inv stale L1/L2
    nbar++;
    unsigned long long cum = sh_sum & MASK44;
    unsigned long long dvf = cum - prevc[par];
    prevc[par] = cum;
    return dvf;
  };

  const double WOPT = 2.0 / (1.0 + 3.14159265358979323846 / 66.0);

  barrier_payload(false);  // x0 init visible everywhere

  int it = 0;
  double dv_tot = 0.0;
  for (;;) {
    const double* __restrict__ xo = (it & 1) ? x1 : x0;
    double* __restrict__ xn       = (it & 1) ? x0 : x1;

    // ---- stage planes z-1, z+1 (double2) + z+-2 black-parity halves ----
    {
      if (z >= 1) {
        const double2* src = (const double2*)(xo + (size_t)(z - 1) * PLANE);
        for (int o = tid; o < PLANE / 2; o += NTHR) {
          double2 v = src[o];
          P[0][2 * o] = v.x; P[0][2 * o + 1] = v.y;
        }
      }
      if (z <= NI - 2) {
        const double2* src = (const double2*)(xo + (size_t)(z + 1) * PLANE);
        for (int o = tid; o < PLANE / 2; o += NTHR) {
          double2 v = src[o];
          P[2][2 * o] = v.x; P[2][2 * o + 1] = v.y;
        }
      }
      const int pb = (z + 1) & 1;   // k parity bit for halo-black positions
      const bool hm = (z >= 2), hp = (z <= NI - 3);
      for (int c = tid; c < HPL; c += NTHR) {
        int j = c / 33;
        int k = ((c - 33 * j) << 1) + (pb ^ (j & 1));
        int o = NJK * j + k;
        if (hm) H[0][c] = xo[(size_t)(z - 2) * PLANE + o];
        if (hp) H[1][c] = xo[(size_t)(z + 2) * PLANE + o];
      }
    }
    __syncthreads();

    double acc = 0.0;
    // ---- black updates, in place in LDS, planes z-1, z, z+1 ----
    {
      const int n = cntB[0];
      for (int p = tid; p < n; p += NTHR) {
        const int o = (int)lsB[0][p];
        int j = o / NJK, k = o - j * NJK;
        double xi = P[0][o];
        double nb = ((((P[0][o - 1] + P[0][o + 1]) + P[0][o - NJK])
                    + P[0][o + NJK]) + H[0][33 * j + (k >> 1)]) + P[1][o];
        double adj = (WOPT * (nb - 6.0 * xi)) / 6.0;
        P[0][o] = xi + adj;
      }
    }
    {
      const int n = cntB[1];
      for (int p = tid; p < n; p += NTHR) {
        const int o = (int)lsB[1][p];
        double xi = P[1][o];
        double nb = ((((P[1][o - 1] + P[1][o + 1]) + P[1][o - NJK])
                    + P[1][o + NJK]) + P[0][o]) + P[2][o];
        double adj = (WOPT * (nb - 6.0 * xi)) / 6.0;
        P[1][o] = xi + adj;
        acc += fabs(adj);
      }
    }
    {
      const int n = cntB[2];
      for (int p = tid; p < n; p += NTHR) {
        const int o = (int)lsB[2][p];
        int j = o / NJK, k = o - j * NJK;
        double xi = P[2][o];
        double nb = ((((P[2][o - 1] + P[2][o + 1]) + P[2][o - NJK])
                    + P[2][o + NJK]) + P[1][o]) + H[1][33 * j + (k >> 1)];
        double adj = (WOPT * (nb - 6.0 * xi)) / 6.0;
        P[2][o] = xi + adj;
      }
    }
    __syncthreads();  // all black updates visible in LDS

    // ---- red update, own plane (reads black-updated P) ----
    for (int p = tid; p < cntR; p += NTHR) {
      const int o = (int)lsR[p];
      double xi = P[1][o];
      double nb = ((((P[1][o - 1] + P[1][o + 1]) + P[1][o - NJK])
                  + P[1][o + NJK]) + P[0][o]) + P[2][o];
      double adj = (WOPT * (nb - 6.0 * xi)) / 6.0;
      P[1][o] = xi + adj;
      acc += fabs(adj);
    }
    __syncthreads();  // red done before write-back reads P[1]

    // ---- write own plane back (coalesced, cached; wbl2 at barrier) ----
    {
      double2* dst = (double2*)(xn + (size_t)z * PLANE);
      for (int o = tid; o < PLANE / 2; o += NTHR) {
        double2 v; v.x = P[1][2 * o]; v.y = P[1][2 * o + 1];
        dst[o] = v;
      }
    }

    // ---- block dv reduce (fixed order) ----
    double a = acc;
    #pragma unroll
    for (int m = 32; m >= 1; m >>= 1) a += __shfl_xor(a, m, 64);
    if (lane == 0) redw[wid] = a;

    unsigned long long dvf = barrier_payload(true);
    dv_tot = (double)dvf * (1.0 / 1048576.0);
    ++it;
    // continue iff (dv >= 0.05 && it <= 500); uniform across all blocks
    if (!((dv_tot >= 0.05) && (it <= 500))) break;
  }

  // ---- epilogue: crop padding from final buffer, write lap + iters + dv ----
  const double* __restrict__ xf = (it & 1) ? x1 : x0;
  const int gtid = bid * NTHR + tid;
  const int NTTH = NBLK * NTHR;
  for (int o = gtid; o < NOUT; o += NTTH) {
    int b   = o >> 18;
    int rem = o & 262143;
    int zi  = rem >> 12;
    int yi  = (rem >> 6) & 63;
    int xi2 = rem & 63;
    long fi = ((long)(b * 66 + zi + 1) * 66 + (yi + 1)) * 66 + (xi2 + 1);
    out[o] = (float)xf[fi];
  }
  if (gtid == 0) {
    out[NOUT]     = (float)it;
    out[NOUT + 1] = (float)dv_tot;
  }
}

extern "C" void kernel_launch(void* const* d_in, const int* in_sizes, int n_in,
                              void* d_out, int out_size, void* d_ws, size_t ws_size,
                              hipStream_t stream) {
  const float* img = (const float*)d_in[0];
  float* out = (float*)d_out;
  char* ws = (char*)d_ws;
  double*             x0   = (double*)ws;
  double*             x1   = (double*)(ws + (size_t)NTOT * 8);
  unsigned long long* ctrl = (unsigned long long*)(ws + (size_t)NTOT * 16);

  sor_init_ctrl<<<1, 256, 0, stream>>>(ctrl);
  sor_main<<<NBLK, NTHR, 0, stream>>>(img, x0, x1, ctrl, out);
}

// Round 8
// 1524.889 us; speedup vs baseline: 3.0119x; 3.0119x over previous
//
#include <hip/hip_runtime.h>
#include <cstdint>

// ---------------------------------------------------------------------------
// Red-black SOR Laplace solver, persistent kernel, f64, ONE barrier/iter,
// LDS-staged stencil + dv folded into the barrier payload.
// Round 8: revert to round-6 sc1 coherence (round-7 fences regressed 2.3x);
// add (a) manual-MLP staging: all ~16 staging loads issued to registers
// before any LDS write (round-6 was a load->ds_write latency chain), and
// (b) persistent own plane in LDS (never re-staged).
// Stop when !(dv >= 0.05 && it <= 500)  [jax.lax.while_loop semantics].
// ---------------------------------------------------------------------------

#define NBLK 132
#define NTHR 1024
#define NW   (NTHR / 64)

constexpr int NJK   = 66;
constexpr int PLANE = 66 * 66;          // 4356
constexpr int HPL   = PLANE / 2;        // 2178
constexpr int NI    = 132;
constexpr int NTOT  = NI * PLANE;       // 574992
constexpr int CAPL  = HPL;              // list cap per color per plane
constexpr int NOUT  = 2 * 64 * 64 * 64; // 524288
constexpr int CTRL_U64 = 512;           // 32 lines x 16 u64 (128 B spacing)
constexpr unsigned long long CNT1   = 1ull << 44;
constexpr unsigned long long MASK44 = CNT1 - 1ull;

__global__ void sor_init_ctrl(unsigned long long* ctrl) {
  for (int i = threadIdx.x; i < CTRL_U64; i += blockDim.x) ctrl[i] = 0ull;
}

__device__ __forceinline__ double cload(const double* p) {
  return __hip_atomic_load(p, __ATOMIC_RELAXED, __HIP_MEMORY_SCOPE_AGENT);
}
__device__ __forceinline__ void cstore(double* p, double v) {
  __hip_atomic_store(p, v, __ATOMIC_RELAXED, __HIP_MEMORY_SCOPE_AGENT);
}

// padded flat coords -> original image flat index, or -1 if pad voxel
__device__ __forceinline__ int pad_label_idx(int ii, int jj, int kk) {
  int b  = (ii >= 66) ? 1 : 0;
  int pz = ii - 66 * b;
  if (pz < 1 || pz > 64 || jj < 1 || jj > 64 || kk < 1 || kk > 64) return -1;
  return ((b * 64 + (pz - 1)) * 64 + (jj - 1)) * 64 + (kk - 1);
}

__global__ __launch_bounds__(NTHR, 1)
void sor_main(const float* __restrict__ img, double* __restrict__ x0,
              double* __restrict__ x1, unsigned long long* __restrict__ ctrl,
              float* __restrict__ out) {
  __shared__ double P[3][PLANE];          // planes z-1, z, z+1 (104544 B)
  __shared__ double H[2][HPL];            // black-parity halves of z-2, z+2
  __shared__ unsigned short lsB[3][CAPL]; // black lists, planes z-1,z,z+1
  __shared__ unsigned short lsR[CAPL];    // red list, own plane
  __shared__ unsigned wsum[NW], woff[NW];
  __shared__ unsigned tot;
  __shared__ double redw[NW];
  __shared__ unsigned long long sh_sum;

  const int tid = threadIdx.x, bid = blockIdx.x;
  const int lane = tid & 63, wid = tid >> 6;
  const int z = bid;

  // ---- init own plane: global x0 AND persistent LDS copy P[1] ----
  {
    double* dst = x0 + (size_t)z * PLANE;
    for (int o = tid; o < PLANE; o += NTHR) {
      int j = o / NJK, k = o - j * NJK;
      int li = pad_label_idx(z, j, k);
      float L = (li >= 0) ? img[li] : 0.0f;
      double v = (L == 3.0f) ? 1.0 : 0.0;
      cstore(&dst[o], v);
      P[1][o] = v;
    }
  }

  // ---- build gm lists: black for z-1,z,z+1; red for z (stable o-order) ----
  int cntB[3], cntR = 0;
  const int CH = (PLANE + NTHR - 1) / NTHR;
  for (int pass = 0; pass < 4; ++pass) {
    const int zz = (pass < 3) ? (z - 1 + pass) : z;
    const int wpar = (pass < 3) ? 0 : 1;
    unsigned short* list = (pass < 3) ? lsB[pass] : lsR;
    const bool ok = (zz >= 0 && zz < NI);
    int c0 = tid * CH;
    int c1 = (c0 + CH < PLANE) ? (c0 + CH) : PLANE;
    unsigned cnt = 0;
    if (ok) {
      for (int o = c0; o < c1; ++o) {
        int j = o / NJK, k = o - j * NJK;
        if (((zz + j + k) & 1) != wpar) continue;
        int li = pad_label_idx(zz, j, k);
        float L = (li >= 0) ? img[li] : 0.0f;
        if (L == 1.0f) cnt++;
      }
    }
    unsigned incl = cnt;
    #pragma unroll
    for (int m = 1; m < 64; m <<= 1) {
      unsigned t = __shfl_up(incl, m, 64);
      if (lane >= m) incl += t;
    }
    __syncthreads();
    if (lane == 63) wsum[wid] = incl;
    __syncthreads();
    if (tid == 0) {
      unsigned a = 0;
      for (int w = 0; w < NW; ++w) { unsigned c = wsum[w]; woff[w] = a; a += c; }
      tot = a;
    }
    __syncthreads();
    unsigned p = (incl - cnt) + woff[wid];
    if (ok) {
      for (int o = c0; o < c1; ++o) {
        int j = o / NJK, k = o - j * NJK;
        if (((zz + j + k) & 1) != wpar) continue;
        int li = pad_label_idx(zz, j, k);
        float L = (li >= 0) ? img[li] : 0.0f;
        if (L == 1.0f) list[p++] = (unsigned short)o;
      }
    }
    __syncthreads();
    if (pass < 3) cntB[pass] = (int)tot; else cntR = (int)tot;
  }

  // ---- barrier bookkeeping: parity line sets, fixed-point dv payload ----
  unsigned tgt[2] = {0u, 0u};
  unsigned long long prevc[2] = {0ull, 0ull};
  unsigned nbar = 0;

  auto barrier_payload = [&](bool withdv) -> unsigned long long {
    const unsigned par = nbar & 1u;
    tgt[par] += (unsigned)NBLK;
    __syncthreads();           // all waves' sc1 stores complete; redw ready
    if (tid == 0) {
      unsigned long long pay = CNT1;
      if (withdv) {
        double s = redw[0];
        #pragma unroll
        for (int w = 1; w < NW; ++w) s += redw[w];
        pay += (unsigned long long)(s * 1048576.0 + 0.5);
      }
      __hip_atomic_fetch_add(&ctrl[(par * 16u + (unsigned)(bid & 15)) * 16u],
                             pay, __ATOMIC_RELAXED, __HIP_MEMORY_SCOPE_AGENT);
    }
    if (tid < 16) {
      const unsigned long long t64 = (unsigned long long)tgt[par] << 44;
      for (;;) {
        unsigned long long v =
            __hip_atomic_load(&ctrl[(par * 16u + (unsigned)tid) * 16u],
                              __ATOMIC_RELAXED, __HIP_MEMORY_SCOPE_AGENT);
        v += __shfl_xor(v, 1, 64);  v += __shfl_xor(v, 2, 64);
        v += __shfl_xor(v, 4, 64);  v += __shfl_xor(v, 8, 64);
        if (v >= t64) { if (tid == 0) sh_sum = v; break; }
        __builtin_amdgcn_s_sleep(1);
      }
    }
    __syncthreads();
    nbar++;
    unsigned long long cum = sh_sum & MASK44;
    unsigned long long dvf = cum - prevc[par];
    prevc[par] = cum;
    return dvf;
  };

  const double WOPT = 2.0 / (1.0 + 3.14159265358979323846 / 66.0);

  barrier_payload(false);  // x0 init visible everywhere

  int it = 0;
  double dv_tot = 0.0;
  for (;;) {
    const double* __restrict__ xo = (it & 1) ? x1 : x0;
    double* __restrict__ xn       = (it & 1) ? x0 : x1;

    // ---- stage z-1, z+1 planes + z+-2 black-parity halves, max MLP:
    //      issue ALL loads to registers, then ALL LDS writes ----
    {
      const bool zm = (z >= 1), zp = (z <= NI - 2);
      const bool hm = (z >= 2), hp = (z <= NI - 3);
      const double* __restrict__ sm = xo + (size_t)(z - 1) * PLANE;
      const double* __restrict__ sp = xo + (size_t)(z + 1) * PLANE;
      const int pb = (z + 1) & 1;   // k parity bit for halo-black positions
      int ho0, ho1, ho2;
      {
        int c = tid;          int j = c / 33;
        ho0 = NJK * j + (((c - 33 * j) << 1) + (pb ^ (j & 1)));
        c = tid + 1024;       j = c / 33;
        ho1 = NJK * j + (((c - 33 * j) << 1) + (pb ^ (j & 1)));
        c = tid + 2048;       j = c / 33;
        ho2 = NJK * j + (((c - 33 * j) << 1) + (pb ^ (j & 1)));
      }
      const bool t260 = (tid < PLANE - 4096);   // 260 tail threads
      const bool t130 = (tid < HPL - 2048);     // 130 tail threads

      double a0 = 0, a1 = 0, a2 = 0, a3 = 0, a4 = 0;
      double b0 = 0, b1 = 0, b2 = 0, b3 = 0, b4 = 0;
      double h0a = 0, h0b = 0, h0c = 0, h1a = 0, h1b = 0, h1c = 0;
      if (zm) {
        a0 = cload(&sm[tid]);        a1 = cload(&sm[tid + 1024]);
        a2 = cload(&sm[tid + 2048]); a3 = cload(&sm[tid + 3072]);
        if (t260) a4 = cload(&sm[tid + 4096]);
      }
      if (zp) {
        b0 = cload(&sp[tid]);        b1 = cload(&sp[tid + 1024]);
        b2 = cload(&sp[tid + 2048]); b3 = cload(&sp[tid + 3072]);
        if (t260) b4 = cload(&sp[tid + 4096]);
      }
      if (hm) {
        const double* __restrict__ s2 = xo + (size_t)(z - 2) * PLANE;
        h0a = cload(&s2[ho0]); h0b = cload(&s2[ho1]);
        if (t130) h0c = cload(&s2[ho2]);
      }
      if (hp) {
        const double* __restrict__ s2 = xo + (size_t)(z + 2) * PLANE;
        h1a = cload(&s2[ho0]); h1b = cload(&s2[ho1]);
        if (t130) h1c = cload(&s2[ho2]);
      }
      // ---- LDS writes (consume loads; compiler emits vmcnt staircase) ----
      if (zm) {
        P[0][tid] = a0;        P[0][tid + 1024] = a1;
        P[0][tid + 2048] = a2; P[0][tid + 3072] = a3;
        if (t260) P[0][tid + 4096] = a4;
      }
      if (zp) {
        P[2][tid] = b0;        P[2][tid + 1024] = b1;
        P[2][tid + 2048] = b2; P[2][tid + 3072] = b3;
        if (t260) P[2][tid + 4096] = b4;
      }
      if (hm) {
        H[0][tid] = h0a; H[0][tid + 1024] = h0b;
        if (t130) H[0][tid + 2048] = h0c;
      }
      if (hp) {
        H[1][tid] = h1a; H[1][tid + 1024] = h1b;
        if (t130) H[1][tid + 2048] = h1c;
      }
    }
    __syncthreads();

    double acc = 0.0;
    // ---- black updates, in place in LDS, planes z-1, z, z+1 ----
    {
      const int n = cntB[0];
      for (int p = tid; p < n; p += NTHR) {
        const int o = (int)lsB[0][p];
        int j = o / NJK, k = o - j * NJK;
        double xi = P[0][o];
        double nb = ((((P[0][o - 1] + P[0][o + 1]) + P[0][o - NJK])
                    + P[0][o + NJK]) + H[0][33 * j + (k >> 1)]) + P[1][o];
        double adj = (WOPT * (nb - 6.0 * xi)) / 6.0;
        P[0][o] = xi + adj;
      }
    }
    {
      const int n = cntB[1];
      for (int p = tid; p < n; p += NTHR) {
        const int o = (int)lsB[1][p];
        double xi = P[1][o];
        double nb = ((((P[1][o - 1] + P[1][o + 1]) + P[1][o - NJK])
                    + P[1][o + NJK]) + P[0][o]) + P[2][o];
        double adj = (WOPT * (nb - 6.0 * xi)) / 6.0;
        P[1][o] = xi + adj;
        acc += fabs(adj);
      }
    }
    {
      const int n = cntB[2];
      for (int p = tid; p < n; p += NTHR) {
        const int o = (int)lsB[2][p];
        int j = o / NJK, k = o - j * NJK;
        double xi = P[2][o];
        double nb = ((((P[2][o - 1] + P[2][o + 1]) + P[2][o - NJK])
                    + P[2][o + NJK]) + P[1][o]) + H[1][33 * j + (k >> 1)];
        double adj = (WOPT * (nb - 6.0 * xi)) / 6.0;
        P[2][o] = xi + adj;
      }
    }
    __syncthreads();  // all black updates visible in LDS

    // ---- red update, own plane (reads black-updated P) ----
    for (int p = tid; p < cntR; p += NTHR) {
      const int o = (int)lsR[p];
      double xi = P[1][o];
      double nb = ((((P[1][o - 1] + P[1][o + 1]) + P[1][o - NJK])
                  + P[1][o + NJK]) + P[0][o]) + P[2][o];
      double adj = (WOPT * (nb - 6.0 * xi)) / 6.0;
      P[1][o] = xi + adj;
      acc += fabs(adj);
    }
    __syncthreads();  // red done before write-back reads P[1]

    // ---- write own plane back (coalesced sc1; drained at barrier) ----
    {
      double* dst = xn + (size_t)z * PLANE;
      for (int o = tid; o < PLANE; o += NTHR) cstore(&dst[o], P[1][o]);
    }

    // ---- block dv reduce (fixed order) ----
    double a = acc;
    #pragma unroll
    for (int m = 32; m >= 1; m >>= 1) a += __shfl_xor(a, m, 64);
    if (lane == 0) redw[wid] = a;

    unsigned long long dvf = barrier_payload(true);
    dv_tot = (double)dvf * (1.0 / 1048576.0);
    ++it;
    // continue iff (dv >= 0.05 && it <= 500); uniform across all blocks
    if (!((dv_tot >= 0.05) && (it <= 500))) break;
  }

  // ---- epilogue: crop padding from final buffer, write lap + iters + dv ----
  const double* __restrict__ xf = (it & 1) ? x1 : x0;
  const int gtid = bid * NTHR + tid;
  const int NTTH = NBLK * NTHR;
  for (int o = gtid; o < NOUT; o += NTTH) {
    int b   = o >> 18;
    int rem = o & 262143;
    int zi  = rem >> 12;
    int yi  = (rem >> 6) & 63;
    int xi2 = rem & 63;
    long fi = ((long)(b * 66 + zi + 1) * 66 + (yi + 1)) * 66 + (xi2 + 1);
    out[o] = (float)cload(&xf[fi]);
  }
  if (gtid == 0) {
    out[NOUT]     = (float)it;
    out[NOUT + 1] = (float)dv_tot;
  }
}

extern "C" void kernel_launch(void* const* d_in, const int* in_sizes, int n_in,
                              void* d_out, int out_size, void* d_ws, size_t ws_size,
                              hipStream_t stream) {
  const float* img = (const float*)d_in[0];
  float* out = (float*)d_out;
  char* ws = (char*)d_ws;
  double*             x0   = (double*)ws;
  double*             x1   = (double*)(ws + (size_t)NTOT * 8);
  unsigned long long* ctrl = (unsigned long long*)(ws + (size_t)NTOT * 16);

  sor_init_ctrl<<<1, 256, 0, stream>>>(ctrl);
  sor_main<<<NBLK, NTHR, 0, stream>>>(img, x0, x1, ctrl, out);
}